// Round 10
// baseline (262.313 us; speedup 1.0000x reference)
//
#include <hip/hip_runtime.h>
#include <hip/hip_fp16.h>
#include <stdint.h>

// AQT int8 MLP: M=8192, C=1024, H=4096. All I/O float32.
// Exact path: fake_quant values are q/s (integer q), so xq@wq is exact in int32 MFMA.
// 4 dispatches: stats -> quant(x,W1t,W2t) -> GEMM1(h fp16-frag + block hmax)
//            -> GEMM2 (fused: hmax reduce + on-the-fly h quant + GEMM + bias).
//
// int8 operands in MFMA-FRAGMENT ORDER: frag = 1KB = 32 rows x 32 k;
//   byte lane*16+j <-> (row=lane&31, k=(lane>>5)*16+j); frag id = rowblk*(K/32)+kblk.
// h stored fp16 in fragment order: frag = 2KB; halfword ((k>>4)*32+r)*16+(k&15),
//   so GEMM2 staging lane l reads one contiguous 32B at frag*2048 + l*32.

#define EPSQ 1e-6f
typedef int v4i __attribute__((ext_vector_type(4)));
typedef int v16i __attribute__((ext_vector_type(16)));

__device__ __forceinline__ int8_t quant1(float x, float s) {
  return (int8_t)(int)fminf(fmaxf(rintf(x * s), -127.f), 127.f);
}
__device__ __forceinline__ void async16(const int8_t* g, int8_t* l) {
  __builtin_amdgcn_global_load_lds(
      (const __attribute__((address_space(1))) void*)g,
      (__attribute__((address_space(3))) void*)l, 16, 0, 0);
}
__device__ __forceinline__ unsigned short f2h(float f) {
  __half h = __float2half(f);
  return *(unsigned short*)&h;
}
__device__ __forceinline__ float h2f(unsigned short u) {
  __half h = *(__half*)&u;
  return __half2float(h);
}
__device__ __forceinline__ float4 max4(float4 m, float4 v) {
  m.x = fmaxf(m.x, fabsf(v.x)); m.y = fmaxf(m.y, fabsf(v.y));
  m.z = fmaxf(m.z, fabsf(v.z)); m.w = fmaxf(m.w, fabsf(v.w));
  return m;
}

// ===== dispatch 1: stats. W1: 16 rowsplits x 4 colgroups; W2: 64 rowsplits;
// x masked absmax: 1024 blk. =====
__global__ __launch_bounds__(256) void k_stats(
    const float* __restrict__ x, const float* __restrict__ mask,
    const float* __restrict__ W1, const float* __restrict__ W2,
    float* __restrict__ pmaxX, float* __restrict__ pcm1, float* __restrict__ pcm2) {
  const int bx = blockIdx.x, tid = threadIdx.x;
  if (bx < 64) {                       // W1 [1024,4096]
    const int sp = bx & 15, cg = bx >> 4;
    const int col = cg * 1024 + tid * 4;
    float4 m = {0.f, 0.f, 0.f, 0.f};
#pragma unroll 8
    for (int r = 0; r < 64; ++r)
      m = max4(m, *(const float4*)(W1 + (size_t)(sp * 64 + r) * 4096 + col));
    *(float4*)(pcm1 + sp * 4096 + col) = m;
  } else if (bx < 128) {               // W2 [4096,1024]
    const int sp = bx - 64;
    const int col = tid * 4;
    float4 m = {0.f, 0.f, 0.f, 0.f};
#pragma unroll 8
    for (int r = 0; r < 64; ++r)
      m = max4(m, *(const float4*)(W2 + (size_t)(sp * 64 + r) * 1024 + col));
    *(float4*)(pcm2 + sp * 1024 + col) = m;
  } else {                             // masked absmax of x -> per-block partial
    __shared__ float red[4];
    const int b = bx - 128;            // 1024 blocks
    float lmax = 0.f;
    for (int c = b * 256 + tid; c < 1048576; c += 262144) {
      size_t idx = (size_t)c * 8;
      float mk = fabsf(mask[idx >> 10]);
      float4 m4 = {0.f, 0.f, 0.f, 0.f};
      m4 = max4(m4, *(const float4*)(x + idx));
      m4 = max4(m4, *(const float4*)(x + idx + 4));
      lmax = fmaxf(lmax, fmaxf(fmaxf(m4.x, m4.y), fmaxf(m4.z, m4.w)) * mk);
    }
    for (int s = 32; s; s >>= 1) lmax = fmaxf(lmax, __shfl_down(lmax, s));
    if ((tid & 63) == 0) red[tid >> 6] = lmax;
    __syncthreads();
    if (tid == 0)
      pmaxX[b] = fmaxf(fmaxf(red[0], red[1]), fmaxf(red[2], red[3]));
  }
}

// ===== dispatch 2: quantize x (2048 blk, frag order), W1->qW1t (256), W2->qW2t (256)
__global__ __launch_bounds__(256) void k_quant(
    const float* __restrict__ x, const float* __restrict__ W1, const float* __restrict__ W2,
    const float* __restrict__ pmaxX, const float* __restrict__ pcm1, const float* __restrict__ pcm2,
    int8_t* __restrict__ qx, int8_t* __restrict__ qw1, int8_t* __restrict__ qw2,
    float* __restrict__ cm1, float* __restrict__ cm2, float* __restrict__ scG) {
  const int bx = blockIdx.x, tid = threadIdx.x;
  if (bx < 2048) {                     // x [8192,1024] -> qx frag order
    __shared__ float red[4];
    float v = fmaxf(fmaxf(pmaxX[tid], pmaxX[tid + 256]),
                    fmaxf(pmaxX[tid + 512], pmaxX[tid + 768]));
    for (int s = 32; s; s >>= 1) v = fmaxf(v, __shfl_down(v, s));
    if ((tid & 63) == 0) red[tid >> 6] = v;
    __syncthreads();
    const float xmax = fmaxf(fmaxf(red[0], red[1]), fmaxf(red[2], red[3]));
    if (bx == 0 && tid == 0) scG[0] = xmax;
    const float s = 127.0f / fmaxf(xmax, EPSQ);
    const int wave = tid >> 6, lane = tid & 63;
    const int f = bx * 4 + wave;                   // frag id; Kf = 1024/32 = 32
    const int r = (f >> 5) * 32 + (lane & 31);
    const int k = (f & 31) * 32 + (lane >> 5) * 16;
    const float4* src = (const float4*)(x + (size_t)r * 1024 + k);
    union { int8_t p[16]; uint4 v; } u;
#pragma unroll
    for (int i = 0; i < 4; ++i) {
      float4 fv = src[i];
      u.p[4 * i] = quant1(fv.x, s);     u.p[4 * i + 1] = quant1(fv.y, s);
      u.p[4 * i + 2] = quant1(fv.z, s); u.p[4 * i + 3] = quant1(fv.w, s);
    }
    *(uint4*)(qx + (size_t)f * 1024 + lane * 16) = u.v;
  } else if (bx < 2304) {              // W1 [1024,4096] -> qw1t frags [4096 n, 1024 k]
    int id = (bx - 2048) * 256 + tid;  // 65536 tasks: 4 cols x 16 k each
    int n4 = id & 1023, kc = id >> 10; // col=n4*4, kc in 0..63 (16-k chunks)
    const int col = n4 * 4;
    float4 cm = {0.f, 0.f, 0.f, 0.f};
#pragma unroll
    for (int sp = 0; sp < 16; ++sp) {
      float4 p = *(const float4*)(pcm1 + sp * 4096 + col);
      cm.x = fmaxf(cm.x, p.x); cm.y = fmaxf(cm.y, p.y);
      cm.z = fmaxf(cm.z, p.z); cm.w = fmaxf(cm.w, p.w);
    }
    if (kc == 0) *(float4*)(cm1 + col) = cm;
    const float s0 = 127.0f / fmaxf(cm.x, EPSQ), s1 = 127.0f / fmaxf(cm.y, EPSQ);
    const float s2 = 127.0f / fmaxf(cm.z, EPSQ), s3 = 127.0f / fmaxf(cm.w, EPSQ);
    union { int8_t p[16]; uint4 v; } u0, u1, u2, u3;
#pragma unroll
    for (int j = 0; j < 16; ++j) {
      float4 f = *(const float4*)(W1 + (size_t)(kc * 16 + j) * 4096 + col);
      u0.p[j] = quant1(f.x, s0); u1.p[j] = quant1(f.y, s1);
      u2.p[j] = quant1(f.z, s2); u3.p[j] = quant1(f.w, s3);
    }
    // frag-order dest: frag=((col>>5)*(1024/32) + (kc>>1)), half=(kc&1)
    int8_t* base = qw1 + ((size_t)(col >> 5) * 32 + (kc >> 1)) * 1024 +
                   (kc & 1) * 512 + (col & 31) * 16;
    *(uint4*)(base) = u0.v;      *(uint4*)(base + 16) = u1.v;
    *(uint4*)(base + 32) = u2.v; *(uint4*)(base + 48) = u3.v;
  } else {                             // W2 [4096,1024] -> qw2t frags [1024 n, 4096 k]
    int id = (bx - 2304) * 256 + tid;  // 65536 tasks
    int n4 = id & 255, kc = id >> 8;   // col=n4*4, kc in 0..255
    const int col = n4 * 4;
    float4 cm = {0.f, 0.f, 0.f, 0.f};
#pragma unroll
    for (int sp = 0; sp < 64; ++sp) {
      float4 p = *(const float4*)(pcm2 + sp * 1024 + col);
      cm.x = fmaxf(cm.x, p.x); cm.y = fmaxf(cm.y, p.y);
      cm.z = fmaxf(cm.z, p.z); cm.w = fmaxf(cm.w, p.w);
    }
    if (kc == 0) *(float4*)(cm2 + col) = cm;
    const float s0 = 127.0f / fmaxf(cm.x, EPSQ), s1 = 127.0f / fmaxf(cm.y, EPSQ);
    const float s2 = 127.0f / fmaxf(cm.z, EPSQ), s3 = 127.0f / fmaxf(cm.w, EPSQ);
    union { int8_t p[16]; uint4 v; } u0, u1, u2, u3;
#pragma unroll
    for (int j = 0; j < 16; ++j) {
      float4 f = *(const float4*)(W2 + (size_t)(kc * 16 + j) * 1024 + col);
      u0.p[j] = quant1(f.x, s0); u1.p[j] = quant1(f.y, s1);
      u2.p[j] = quant1(f.z, s2); u3.p[j] = quant1(f.w, s3);
    }
    int8_t* base = qw2 + ((size_t)(col >> 5) * 128 + (kc >> 1)) * 1024 +
                   (kc & 1) * 512 + (col & 31) * 16;
    *(uint4*)(base) = u0.v;      *(uint4*)(base + 16) = u1.v;
    *(uint4*)(base + 32) = u2.v; *(uint4*)(base + 48) = u3.v;
  }
}

// ====== GEMM1: qx [M=8192, K=1024] x qw1t [N=4096, K], 128x128 block, KF=2 dbuf.
// Output: h fp16 in FRAGMENT ORDER + per-block masked hmax -> pmaxH. ======
__global__ __launch_bounds__(256, 5) void gemm1(
    const int8_t* __restrict__ A, const int8_t* __restrict__ Bt,
    const float* __restrict__ sxp, const float* __restrict__ cmax,
    const float* __restrict__ bias, const float* __restrict__ mask,
    unsigned short* __restrict__ hfrag, float* __restrict__ pmaxH) {
  constexpr int KF = 2, Kf = 32;       // K=1024
  __shared__ __align__(16) int8_t lsA[2][KF * 4096];
  __shared__ __align__(16) int8_t lsB[2][KF * 4096];
  __shared__ float red[4];
  const int tid = threadIdx.x;
  const int wave = tid >> 6, lane = tid & 63;
  const int m0 = blockIdx.x * 128, n0 = blockIdx.y * 128;
  const int wm = (wave & 1) * 64, wn = (wave >> 1) * 64;

  v16i acc[2][2] = {};

  const int8_t* gA[KF]; const int8_t* gB[KF];
  int8_t* dA[KF]; int8_t* dB[KF];
#pragma unroll
  for (int kc = 0; kc < KF; ++kc) {
    gA[kc] = A + ((size_t)((m0 >> 5) + wave) * Kf + kc) * 1024 + lane * 16;
    gB[kc] = Bt + ((size_t)((n0 >> 5) + wave) * Kf + kc) * 1024 + lane * 16;
    dA[kc] = lsA[0] + (kc * 4 + wave) * 1024 + lane * 16;
    dB[kc] = lsB[0] + (kc * 4 + wave) * 1024 + lane * 16;
  }

  const int nsteps = 1024 / (32 * KF);
#pragma unroll
  for (int kc = 0; kc < KF; ++kc) { async16(gA[kc], dA[kc]); async16(gB[kc], dB[kc]); }

  const int mI = (wave & 1) * 2, nI = (wave >> 1) * 2;

  for (int kb = 0; kb < nsteps; ++kb) {
    const int cur = kb & 1;
    const int co = cur * (KF * 4096);
    __syncthreads();
    if (kb + 1 < nsteps) {
      const size_t ko = (size_t)(kb + 1) * (KF * 1024);
      const int po = (cur ^ 1) * (KF * 4096);
#pragma unroll
      for (int kc = 0; kc < KF; ++kc) {
        async16(gA[kc] + ko, dA[kc] + po);
        async16(gB[kc] + ko, dB[kc] + po);
      }
    }
#pragma unroll
    for (int kc = 0; kc < KF; ++kc) {
      v4i af[2], bf[2];
#pragma unroll
      for (int mt = 0; mt < 2; ++mt)
        af[mt] = *(const v4i*)(lsA[0] + co + (kc * 4 + mI + mt) * 1024 + lane * 16);
#pragma unroll
      for (int nt = 0; nt < 2; ++nt)
        bf[nt] = *(const v4i*)(lsB[0] + co + (kc * 4 + nI + nt) * 1024 + lane * 16);
#pragma unroll
      for (int mt = 0; mt < 2; ++mt)
#pragma unroll
        for (int nt = 0; nt < 2; ++nt)
          acc[mt][nt] = __builtin_amdgcn_mfma_i32_32x32x32_i8(af[mt], bf[nt], acc[mt][nt], 0, 0, 0);
    }
  }

  // epilogue: C/D layout col=lane&31, row=(reg&3)+8*(reg>>2)+4*(lane>>5).
  // h written fp16 FRAG ORDER: frag=(rowblk*128 + kblk), halfword ((k>>4)*32+r)*16+(k&15)
  const float asc = fmaxf(sxp[0], EPSQ) * (1.0f / 127.0f);
  const int cl = lane & 31;
  const int rbase = 4 * (lane >> 5);

  float bsc[2], bv[2];
#pragma unroll
  for (int nt = 0; nt < 2; ++nt) {
    int col = n0 + wn + nt * 32 + cl;
    bsc[nt] = fmaxf(cmax[col], EPSQ) * (1.0f / 127.0f) * asc;
    bv[nt] = bias[col];
  }

  const int hwoff = (cl >> 4) * 512 + (cl & 15);   // within-frag halfword base for k=cl
  float lmax = 0.f;
#pragma unroll
  for (int mt = 0; mt < 2; ++mt) {
    const size_t rowblk = (size_t)((m0 + wm) >> 5) + mt;
#pragma unroll
    for (int g = 0; g < 4; ++g)
#pragma unroll
      for (int r2 = 0; r2 < 4; ++r2) {
        const int rloc = g * 8 + r2 + rbase;       // row within 32-block
        const int row = m0 + wm + mt * 32 + rloc;
        const float mk = fabsf(mask[row]);
#pragma unroll
        for (int nt = 0; nt < 2; ++nt) {
          const size_t kblk = (size_t)((n0 + wn) >> 5) + nt;
          float v = (float)acc[mt][nt][g * 4 + r2] * bsc[nt] + bv[nt];
          v = fmaxf(v, 0.f);
          hfrag[(rowblk * 128 + kblk) * 1024 + hwoff + rloc * 16] = f2h(v);
          lmax = fmaxf(lmax, v * mk);
        }
      }
  }
  for (int s = 32; s; s >>= 1) lmax = fmaxf(lmax, __shfl_down(lmax, s));
  if (lane == 0) red[wave] = lmax;
  __syncthreads();
  if (tid == 0)
    pmaxH[blockIdx.x * gridDim.y + blockIdx.y] =
        fmaxf(fmaxf(red[0], red[1]), fmaxf(red[2], red[3]));
}

// ====== GEMM2 (fused): hfrag fp16 [M=8192, K=4096] x qw2t [N=1024, K].
// Reduces pmaxH -> hmax; quantizes h on the fly (regs -> ds_write_b128).
// 128x128 block, KF=4 dbuf. Out f32 = deq + bias. ======
__global__ __launch_bounds__(256, 2) void gemm2(
    const unsigned short* __restrict__ hfrag, const int8_t* __restrict__ Bt,
    const float* __restrict__ pmaxH, const float* __restrict__ cmax,
    const float* __restrict__ bias, float* __restrict__ out) {
  constexpr int KF = 4, Kf = 128;      // K=4096
  __shared__ __align__(16) int8_t lsA[2][KF * 4096];
  __shared__ __align__(16) int8_t lsB[2][KF * 4096];
  __shared__ float red[4];
  const int tid = threadIdx.x;
  const int wave = tid >> 6, lane = tid & 63;

  // hmax = max over 2048 pmaxH partials (all GEMM1 blocks; stream-ordered)
  float v = 0.f;
#pragma unroll
  for (int j = 0; j < 8; ++j) v = fmaxf(v, pmaxH[tid + 256 * j]);
  for (int s = 32; s; s >>= 1) v = fmaxf(v, __shfl_down(v, s));
  if (lane == 0) red[wave] = v;
  __syncthreads();
  const float hmax = fmaxf(fmaxf(red[0], red[1]), fmaxf(red[2], red[3]));
  const float sq = 127.0f / fmaxf(hmax, EPSQ);
  const float asc = fmaxf(hmax, EPSQ) * (1.0f / 127.0f);

  const int m0 = blockIdx.x * 128, n0 = blockIdx.y * 128;
  const int wm = (wave & 1) * 64, wn = (wave >> 1) * 64;

  v16i acc[2][2] = {};

  // A staging: lane reads 32B fp16 (one h-frag fragment slice) -> quant -> LDS.
  const uint4* hA = (const uint4*)hfrag;           // frag = 128 uint4
  size_t aIdx[KF]; const int8_t* gB[KF]; int8_t* dA[KF]; int8_t* dB[KF];
#pragma unroll
  for (int kc = 0; kc < KF; ++kc) {
    aIdx[kc] = ((size_t)((m0 >> 5) + wave) * Kf + kc) * 128 + lane * 2;
    gB[kc] = Bt + ((size_t)((n0 >> 5) + wave) * Kf + kc) * 1024 + lane * 16;
    dA[kc] = lsA[0] + (kc * 4 + wave) * 1024 + lane * 16;
    dB[kc] = lsB[0] + (kc * 4 + wave) * 1024 + lane * 16;
  }

  const int nsteps = 4096 / (32 * KF);             // 32
  // prologue: stage step 0
#pragma unroll
  for (int kc = 0; kc < KF; ++kc) {
    uint4 a = hA[aIdx[kc]], b = hA[aIdx[kc] + 1];
    const unsigned short* as = (const unsigned short*)&a;
    const unsigned short* bs = (const unsigned short*)&b;
    union { int8_t p[16]; v4i q; } u;
#pragma unroll
    for (int i = 0; i < 8; ++i) {
      u.p[i] = quant1(h2f(as[i]), sq);
      u.p[i + 8] = quant1(h2f(bs[i]), sq);
    }
    *(v4i*)dA[kc] = u.q;
    async16(gB[kc], dB[kc]);
  }

  const int mI = (wave & 1) * 2, nI = (wave >> 1) * 2;

  for (int kb = 0; kb < nsteps; ++kb) {
    const int cur = kb & 1;
    const int co = cur * (KF * 4096);
    __syncthreads();
    uint4 pa[KF], pb[KF];
    const bool more = (kb + 1 < nsteps);
    const int po = (cur ^ 1) * (KF * 4096);
    if (more) {
#pragma unroll
      for (int kc = 0; kc < KF; ++kc) {
        const size_t ai = aIdx[kc] + (size_t)(kb + 1) * (KF * 128);
        pa[kc] = hA[ai];
        pb[kc] = hA[ai + 1];
        async16(gB[kc] + (size_t)(kb + 1) * (KF * 1024), dB[kc] + po);
      }
    }
#pragma unroll
    for (int kc = 0; kc < KF; ++kc) {
      v4i af[2], bf[2];
#pragma unroll
      for (int mt = 0; mt < 2; ++mt)
        af[mt] = *(const v4i*)(lsA[0] + co + (kc * 4 + mI + mt) * 1024 + lane * 16);
#pragma unroll
      for (int nt = 0; nt < 2; ++nt)
        bf[nt] = *(const v4i*)(lsB[0] + co + (kc * 4 + nI + nt) * 1024 + lane * 16);
#pragma unroll
      for (int mt = 0; mt < 2; ++mt)
#pragma unroll
        for (int nt = 0; nt < 2; ++nt)
          acc[mt][nt] = __builtin_amdgcn_mfma_i32_32x32x32_i8(af[mt], bf[nt], acc[mt][nt], 0, 0, 0);
    }
    if (more) {
#pragma unroll
      for (int kc = 0; kc < KF; ++kc) {
        const unsigned short* as = (const unsigned short*)&pa[kc];
        const unsigned short* bs = (const unsigned short*)&pb[kc];
        union { int8_t p[16]; v4i q; } u;
#pragma unroll
        for (int i = 0; i < 8; ++i) {
          u.p[i] = quant1(h2f(as[i]), sq);
          u.p[i + 8] = quant1(h2f(bs[i]), sq);
        }
        *(v4i*)(dA[kc] + po) = u.q;
      }
    }
  }

  // epilogue: out f32 row-major [8192,1024]
  const int cl = lane & 31;
  const int rbase = 4 * (lane >> 5);
  float bsc[2], bv[2];
#pragma unroll
  for (int nt = 0; nt < 2; ++nt) {
    int col = n0 + wn + nt * 32 + cl;
    bsc[nt] = fmaxf(cmax[col], EPSQ) * (1.0f / 127.0f) * asc;
    bv[nt] = bias[col];
  }
#pragma unroll
  for (int mt = 0; mt < 2; ++mt)
#pragma unroll
    for (int g = 0; g < 4; ++g)
#pragma unroll
      for (int r2 = 0; r2 < 4; ++r2) {
        int row = m0 + wm + mt * 32 + g * 8 + r2 + rbase;
        float* orow = out + (size_t)row * 1024 + n0 + wn + cl;
#pragma unroll
        for (int nt = 0; nt < 2; ++nt)
          orow[nt * 32] = (float)acc[mt][nt][g * 4 + r2] * bsc[nt] + bv[nt];
      }
}

extern "C" void kernel_launch(void* const* d_in, const int* in_sizes, int n_in,
                              void* d_out, int out_size, void* d_ws, size_t ws_size,
                              hipStream_t stream) {
  const float* x  = (const float*)d_in[0];   // [8192,1024]
  const float* mk = (const float*)d_in[1];   // [8192]
  const float* W1 = (const float*)d_in[2];   // [1024,4096]
  const float* b1 = (const float*)d_in[3];   // [4096]
  const float* W2 = (const float*)d_in[4];   // [4096,1024]
  const float* b2 = (const float*)d_in[5];   // [1024]
  float* out = (float*)d_out;                // [8192,1024]

  float* scG   = (float*)d_ws;               // [8]
  float* pmaxX = scG + 8;                    // [1024]
  float* pmaxH = pmaxX + 1024;               // [2048]
  float* pcm1  = pmaxH + 2048;               // [16*4096]
  float* pcm2  = pcm1 + 65536;               // [64*1024]
  float* cm1   = pcm2 + 65536;               // [4096]
  float* cm2   = cm1 + 4096;                 // [1024]
  int8_t* qx  = (int8_t*)(cm2 + 1024);           // 8 MiB  frag order
  int8_t* qw1 = qx  + (size_t)8192 * 1024;       // 4 MiB  frag order [4096 n][1024 k]
  int8_t* qw2 = qw1 + (size_t)4096 * 1024;       // 4 MiB  frag order [1024 n][4096 k]
  unsigned short* h = (unsigned short*)(qw2 + (size_t)1024 * 4096);  // 64 MiB fp16 frag order

  k_stats<<<1152, 256, 0, stream>>>(x, mk, W1, W2, pmaxX, pcm1, pcm2);
  k_quant<<<2560, 256, 0, stream>>>(x, W1, W2, pmaxX, pcm1, pcm2,
                                    qx, qw1, qw2, cm1, cm2, scG);
  gemm1<<<dim3(64, 32), 256, 0, stream>>>(qx, qw1, scG, cm1, b1, mk, h, pmaxH);
  gemm2<<<dim3(64, 8), 256, 0, stream>>>(h, qw2, pmaxH, cm2, b2, out);
}

// Round 11
// 237.981 us; speedup vs baseline: 1.1022x; 1.1022x over previous
//
#include <hip/hip_runtime.h>
#include <hip/hip_fp16.h>
#include <stdint.h>

// AQT int8 MLP: M=8192, C=1024, H=4096. All I/O float32.
// Exact path: fake_quant values are q/s (integer q), so xq@wq is exact in int32 MFMA.
// 4 dispatches: stats -> quant(x,W1t,W2t) -> GEMM1(h fp16-frag + block hmax)
//            -> GEMM2 (fused: hmax reduce + packed magic-quant of h + GEMM + bias).
//
// int8 operands in MFMA-FRAGMENT ORDER: frag = 1KB = 32 rows x 32 k;
//   byte lane*16+j <-> (row=lane&31, k=(lane>>5)*16+j); frag id = rowblk*(K/32)+kblk.
// h stored fp16 in fragment order: frag = 2KB; halfword ((k>>4)*32+r)*16+(k&15),
//   so GEMM2 staging lane l reads one contiguous 32B at frag*2048 + l*32.
// Magic quant: fp32 fma(x,s,1.5*2^23) -> low byte = int8 q (two's complement);
//   fp16 hfma2(h,s,1536) -> low byte of each half = q (h>=0 after relu).

#define EPSQ 1e-6f
typedef int v4i __attribute__((ext_vector_type(4)));
typedef int v16i __attribute__((ext_vector_type(16)));

__device__ __forceinline__ void async16(const int8_t* g, int8_t* l) {
  __builtin_amdgcn_global_load_lds(
      (const __attribute__((address_space(1))) void*)g,
      (__attribute__((address_space(3))) void*)l, 16, 0, 0);
}
__device__ __forceinline__ unsigned short f2h(float f) {
  __half h = __float2half(f);
  return *(unsigned short*)&h;
}
__device__ __forceinline__ float4 max4(float4 m, float4 v) {
  m.x = fmaxf(m.x, fabsf(v.x)); m.y = fmaxf(m.y, fabsf(v.y));
  m.z = fmaxf(m.z, fabsf(v.z)); m.w = fmaxf(m.w, fabsf(v.w));
  return m;
}
// fp32 magic quant: |x*s| <= 127 guaranteed by construction (s = 127/absmax).
__device__ __forceinline__ unsigned qmb(float x, float s) {
  return __float_as_uint(fmaf(x, s, 12582912.0f)) & 0xffu;   // 1.5*2^23
}
__device__ __forceinline__ unsigned q4f(float4 f, float s) {
  return qmb(f.x, s) | (qmb(f.y, s) << 8) | (qmb(f.z, s) << 16) |
         (__float_as_uint(fmaf(f.w, s, 12582912.0f)) << 24);
}
// fp16 packed magic quant: two halfs -> ... -> select low bytes of 4 halfs.
__device__ __forceinline__ unsigned q4h(unsigned ua, unsigned ub,
                                        __half2 s2, __half2 m2) {
  __half2 ha = __hfma2(*(__half2*)&ua, s2, m2);
  __half2 hb = __hfma2(*(__half2*)&ub, s2, m2);
  unsigned va = *(unsigned*)&ha, vb = *(unsigned*)&hb;
#if __has_builtin(__builtin_amdgcn_perm)
  return __builtin_amdgcn_perm(vb, va, 0x06040200u);
#else
  return (va & 0xffu) | ((va >> 8) & 0xff00u) |
         ((vb & 0xffu) << 16) | (((vb >> 8) & 0xff00u) << 16);
#endif
}

// ===== dispatch 1: stats. W1: 16 rowsplits x 4 colgroups; W2: 64 rowsplits;
// x masked absmax: 1024 blk. =====
__global__ __launch_bounds__(256) void k_stats(
    const float* __restrict__ x, const float* __restrict__ mask,
    const float* __restrict__ W1, const float* __restrict__ W2,
    float* __restrict__ pmaxX, float* __restrict__ pcm1, float* __restrict__ pcm2) {
  const int bx = blockIdx.x, tid = threadIdx.x;
  if (bx < 64) {                       // W1 [1024,4096]
    const int sp = bx & 15, cg = bx >> 4;
    const int col = cg * 1024 + tid * 4;
    float4 m = {0.f, 0.f, 0.f, 0.f};
#pragma unroll 8
    for (int r = 0; r < 64; ++r)
      m = max4(m, *(const float4*)(W1 + (size_t)(sp * 64 + r) * 4096 + col));
    *(float4*)(pcm1 + sp * 4096 + col) = m;
  } else if (bx < 128) {               // W2 [4096,1024]
    const int sp = bx - 64;
    const int col = tid * 4;
    float4 m = {0.f, 0.f, 0.f, 0.f};
#pragma unroll 8
    for (int r = 0; r < 64; ++r)
      m = max4(m, *(const float4*)(W2 + (size_t)(sp * 64 + r) * 1024 + col));
    *(float4*)(pcm2 + sp * 1024 + col) = m;
  } else {                             // masked absmax of x -> per-block partial
    __shared__ float red[4];
    const int b = bx - 128;            // 1024 blocks
    float lmax = 0.f;
    for (int c = b * 256 + tid; c < 1048576; c += 262144) {
      size_t idx = (size_t)c * 8;
      float mk = fabsf(mask[idx >> 10]);
      float4 m4 = {0.f, 0.f, 0.f, 0.f};
      m4 = max4(m4, *(const float4*)(x + idx));
      m4 = max4(m4, *(const float4*)(x + idx + 4));
      lmax = fmaxf(lmax, fmaxf(fmaxf(m4.x, m4.y), fmaxf(m4.z, m4.w)) * mk);
    }
    for (int s = 32; s; s >>= 1) lmax = fmaxf(lmax, __shfl_down(lmax, s));
    if ((tid & 63) == 0) red[tid >> 6] = lmax;
    __syncthreads();
    if (tid == 0)
      pmaxX[b] = fmaxf(fmaxf(red[0], red[1]), fmaxf(red[2], red[3]));
  }
}

// ===== dispatch 2: quantize x (2048 blk, frag order), W1->qW1t (256), W2->qW2t (256)
__global__ __launch_bounds__(256) void k_quant(
    const float* __restrict__ x, const float* __restrict__ W1, const float* __restrict__ W2,
    const float* __restrict__ pmaxX, const float* __restrict__ pcm1, const float* __restrict__ pcm2,
    int8_t* __restrict__ qx, int8_t* __restrict__ qw1, int8_t* __restrict__ qw2,
    float* __restrict__ cm1, float* __restrict__ cm2, float* __restrict__ scG) {
  const int bx = blockIdx.x, tid = threadIdx.x;
  if (bx < 2048) {                     // x [8192,1024] -> qx frag order
    __shared__ float red[4];
    float v = fmaxf(fmaxf(pmaxX[tid], pmaxX[tid + 256]),
                    fmaxf(pmaxX[tid + 512], pmaxX[tid + 768]));
    for (int s = 32; s; s >>= 1) v = fmaxf(v, __shfl_down(v, s));
    if ((tid & 63) == 0) red[tid >> 6] = v;
    __syncthreads();
    const float xmax = fmaxf(fmaxf(red[0], red[1]), fmaxf(red[2], red[3]));
    if (bx == 0 && tid == 0) scG[0] = xmax;
    const float s = 127.0f / fmaxf(xmax, EPSQ);
    const int wave = tid >> 6, lane = tid & 63;
    const int f = bx * 4 + wave;                   // frag id; Kf = 1024/32 = 32
    const int r = (f >> 5) * 32 + (lane & 31);
    const int k = (f & 31) * 32 + (lane >> 5) * 16;
    const float4* src = (const float4*)(x + (size_t)r * 1024 + k);
    uint4 o;
    o.x = q4f(src[0], s); o.y = q4f(src[1], s);
    o.z = q4f(src[2], s); o.w = q4f(src[3], s);
    *(uint4*)(qx + (size_t)f * 1024 + lane * 16) = o;
  } else if (bx < 2304) {              // W1 [1024,4096] -> qw1t frags [4096 n, 1024 k]
    int id = (bx - 2048) * 256 + tid;  // 65536 tasks: 4 cols x 16 k each
    int n4 = id & 1023, kc = id >> 10; // col=n4*4, kc in 0..63 (16-k chunks)
    const int col = n4 * 4;
    float4 cm = {0.f, 0.f, 0.f, 0.f};
#pragma unroll
    for (int sp = 0; sp < 16; ++sp) {
      float4 p = *(const float4*)(pcm1 + sp * 4096 + col);
      cm.x = fmaxf(cm.x, p.x); cm.y = fmaxf(cm.y, p.y);
      cm.z = fmaxf(cm.z, p.z); cm.w = fmaxf(cm.w, p.w);
    }
    if (kc == 0) *(float4*)(cm1 + col) = cm;
    const float s0 = 127.0f / fmaxf(cm.x, EPSQ), s1 = 127.0f / fmaxf(cm.y, EPSQ);
    const float s2 = 127.0f / fmaxf(cm.z, EPSQ), s3 = 127.0f / fmaxf(cm.w, EPSQ);
    union { int8_t p[16]; uint4 v; } u0, u1, u2, u3;
#pragma unroll
    for (int j = 0; j < 16; ++j) {
      float4 f = *(const float4*)(W1 + (size_t)(kc * 16 + j) * 4096 + col);
      u0.p[j] = (int8_t)qmb(f.x, s0); u1.p[j] = (int8_t)qmb(f.y, s1);
      u2.p[j] = (int8_t)qmb(f.z, s2); u3.p[j] = (int8_t)qmb(f.w, s3);
    }
    // frag-order dest: frag=((col>>5)*(1024/32) + (kc>>1)), half=(kc&1)
    int8_t* base = qw1 + ((size_t)(col >> 5) * 32 + (kc >> 1)) * 1024 +
                   (kc & 1) * 512 + (col & 31) * 16;
    *(uint4*)(base) = u0.v;      *(uint4*)(base + 16) = u1.v;
    *(uint4*)(base + 32) = u2.v; *(uint4*)(base + 48) = u3.v;
  } else {                             // W2 [4096,1024] -> qw2t frags [1024 n, 4096 k]
    int id = (bx - 2304) * 256 + tid;  // 65536 tasks
    int n4 = id & 255, kc = id >> 8;   // col=n4*4, kc in 0..255
    const int col = n4 * 4;
    float4 cm = {0.f, 0.f, 0.f, 0.f};
#pragma unroll
    for (int sp = 0; sp < 64; ++sp) {
      float4 p = *(const float4*)(pcm2 + sp * 1024 + col);
      cm.x = fmaxf(cm.x, p.x); cm.y = fmaxf(cm.y, p.y);
      cm.z = fmaxf(cm.z, p.z); cm.w = fmaxf(cm.w, p.w);
    }
    if (kc == 0) *(float4*)(cm2 + col) = cm;
    const float s0 = 127.0f / fmaxf(cm.x, EPSQ), s1 = 127.0f / fmaxf(cm.y, EPSQ);
    const float s2 = 127.0f / fmaxf(cm.z, EPSQ), s3 = 127.0f / fmaxf(cm.w, EPSQ);
    union { int8_t p[16]; uint4 v; } u0, u1, u2, u3;
#pragma unroll
    for (int j = 0; j < 16; ++j) {
      float4 f = *(const float4*)(W2 + (size_t)(kc * 16 + j) * 1024 + col);
      u0.p[j] = (int8_t)qmb(f.x, s0); u1.p[j] = (int8_t)qmb(f.y, s1);
      u2.p[j] = (int8_t)qmb(f.z, s2); u3.p[j] = (int8_t)qmb(f.w, s3);
    }
    int8_t* base = qw2 + ((size_t)(col >> 5) * 128 + (kc >> 1)) * 1024 +
                   (kc & 1) * 512 + (col & 31) * 16;
    *(uint4*)(base) = u0.v;      *(uint4*)(base + 16) = u1.v;
    *(uint4*)(base + 32) = u2.v; *(uint4*)(base + 48) = u3.v;
  }
}

// ====== GEMM1: qx [M=8192, K=1024] x qw1t [N=4096, K], 128x128 block, KF=2 dbuf.
// Output: h fp16 in FRAGMENT ORDER + per-block masked hmax -> pmaxH. ======
__global__ __launch_bounds__(256, 5) void gemm1(
    const int8_t* __restrict__ A, const int8_t* __restrict__ Bt,
    const float* __restrict__ sxp, const float* __restrict__ cmax,
    const float* __restrict__ bias, const float* __restrict__ mask,
    unsigned short* __restrict__ hfrag, float* __restrict__ pmaxH) {
  constexpr int KF = 2, Kf = 32;       // K=1024
  __shared__ __align__(16) int8_t lsA[2][KF * 4096];
  __shared__ __align__(16) int8_t lsB[2][KF * 4096];
  __shared__ float red[4];
  const int tid = threadIdx.x;
  const int wave = tid >> 6, lane = tid & 63;
  const int m0 = blockIdx.x * 128, n0 = blockIdx.y * 128;
  const int wm = (wave & 1) * 64, wn = (wave >> 1) * 64;

  v16i acc[2][2] = {};

  const int8_t* gA[KF]; const int8_t* gB[KF];
  int8_t* dA[KF]; int8_t* dB[KF];
#pragma unroll
  for (int kc = 0; kc < KF; ++kc) {
    gA[kc] = A + ((size_t)((m0 >> 5) + wave) * Kf + kc) * 1024 + lane * 16;
    gB[kc] = Bt + ((size_t)((n0 >> 5) + wave) * Kf + kc) * 1024 + lane * 16;
    dA[kc] = lsA[0] + (kc * 4 + wave) * 1024 + lane * 16;
    dB[kc] = lsB[0] + (kc * 4 + wave) * 1024 + lane * 16;
  }

  const int nsteps = 1024 / (32 * KF);
#pragma unroll
  for (int kc = 0; kc < KF; ++kc) { async16(gA[kc], dA[kc]); async16(gB[kc], dB[kc]); }

  const int mI = (wave & 1) * 2, nI = (wave >> 1) * 2;

  for (int kb = 0; kb < nsteps; ++kb) {
    const int cur = kb & 1;
    const int co = cur * (KF * 4096);
    __syncthreads();
    if (kb + 1 < nsteps) {
      const size_t ko = (size_t)(kb + 1) * (KF * 1024);
      const int po = (cur ^ 1) * (KF * 4096);
#pragma unroll
      for (int kc = 0; kc < KF; ++kc) {
        async16(gA[kc] + ko, dA[kc] + po);
        async16(gB[kc] + ko, dB[kc] + po);
      }
    }
#pragma unroll
    for (int kc = 0; kc < KF; ++kc) {
      v4i af[2], bf[2];
#pragma unroll
      for (int mt = 0; mt < 2; ++mt)
        af[mt] = *(const v4i*)(lsA[0] + co + (kc * 4 + mI + mt) * 1024 + lane * 16);
#pragma unroll
      for (int nt = 0; nt < 2; ++nt)
        bf[nt] = *(const v4i*)(lsB[0] + co + (kc * 4 + nI + nt) * 1024 + lane * 16);
#pragma unroll
      for (int mt = 0; mt < 2; ++mt)
#pragma unroll
        for (int nt = 0; nt < 2; ++nt)
          acc[mt][nt] = __builtin_amdgcn_mfma_i32_32x32x32_i8(af[mt], bf[nt], acc[mt][nt], 0, 0, 0);
    }
  }

  // epilogue: C/D layout col=lane&31, row=(reg&3)+8*(reg>>2)+4*(lane>>5).
  // h written fp16 FRAG ORDER: frag=(rowblk*128 + kblk), halfword ((k>>4)*32+r)*16+(k&15)
  const float asc = fmaxf(sxp[0], EPSQ) * (1.0f / 127.0f);
  const int cl = lane & 31;
  const int rbase = 4 * (lane >> 5);

  float bsc[2], bv[2];
#pragma unroll
  for (int nt = 0; nt < 2; ++nt) {
    int col = n0 + wn + nt * 32 + cl;
    bsc[nt] = fmaxf(cmax[col], EPSQ) * (1.0f / 127.0f) * asc;
    bv[nt] = bias[col];
  }

  const int hwoff = (cl >> 4) * 512 + (cl & 15);   // within-frag halfword base for k=cl
  float lmax = 0.f;
#pragma unroll
  for (int mt = 0; mt < 2; ++mt) {
    const size_t rowblk = (size_t)((m0 + wm) >> 5) + mt;
#pragma unroll
    for (int g = 0; g < 4; ++g)
#pragma unroll
      for (int r2 = 0; r2 < 4; ++r2) {
        const int rloc = g * 8 + r2 + rbase;       // row within 32-block
        const int row = m0 + wm + mt * 32 + rloc;
        const float mk = fabsf(mask[row]);
#pragma unroll
        for (int nt = 0; nt < 2; ++nt) {
          const size_t kblk = (size_t)((n0 + wn) >> 5) + nt;
          float v = (float)acc[mt][nt][g * 4 + r2] * bsc[nt] + bv[nt];
          v = fmaxf(v, 0.f);
          hfrag[(rowblk * 128 + kblk) * 1024 + hwoff + rloc * 16] = f2h(v);
          lmax = fmaxf(lmax, v * mk);
        }
      }
  }
  for (int s = 32; s; s >>= 1) lmax = fmaxf(lmax, __shfl_down(lmax, s));
  if (lane == 0) red[wave] = lmax;
  __syncthreads();
  if (tid == 0)
    pmaxH[blockIdx.x * gridDim.y + blockIdx.y] =
        fmaxf(fmaxf(red[0], red[1]), fmaxf(red[2], red[3]));
}

// ====== GEMM2 (fused): hfrag fp16 [M=8192, K=4096] x qw2t [N=1024, K].
// Reduces pmaxH -> hmax; quantizes h on the fly (packed fp16 magic, h>=0).
// 128x128 block, KF=4 dbuf. Out f32 = deq + bias. ======
__global__ __launch_bounds__(256, 2) void gemm2(
    const unsigned short* __restrict__ hfrag, const int8_t* __restrict__ Bt,
    const float* __restrict__ pmaxH, const float* __restrict__ cmax,
    const float* __restrict__ bias, float* __restrict__ out) {
  constexpr int KF = 4, Kf = 128;      // K=4096
  __shared__ __align__(16) int8_t lsA[2][KF * 4096];
  __shared__ __align__(16) int8_t lsB[2][KF * 4096];
  __shared__ float red[4];
  const int tid = threadIdx.x;
  const int wave = tid >> 6, lane = tid & 63;

  // hmax = max over 2048 pmaxH partials (all GEMM1 blocks; stream-ordered)
  float v = 0.f;
#pragma unroll
  for (int j = 0; j < 8; ++j) v = fmaxf(v, pmaxH[tid + 256 * j]);
  for (int s = 32; s; s >>= 1) v = fmaxf(v, __shfl_down(v, s));
  if (lane == 0) red[wave] = v;
  __syncthreads();
  const float hmax = fmaxf(fmaxf(red[0], red[1]), fmaxf(red[2], red[3]));
  const float asc = fmaxf(hmax, EPSQ) * (1.0f / 127.0f);
  const __half sh = __float2half_rn(127.0f / fmaxf(hmax, EPSQ));
  const __half2 s2 = __halves2half2(sh, sh);
  const __half mh = __float2half_rn(1536.0f);
  const __half2 m2 = __halves2half2(mh, mh);

  const int m0 = blockIdx.x * 128, n0 = blockIdx.y * 128;
  const int wm = (wave & 1) * 64, wn = (wave >> 1) * 64;

  v16i acc[2][2] = {};

  // A staging: lane reads 32B fp16 (one h-frag fragment slice) -> packed quant -> LDS.
  const uint4* hA = (const uint4*)hfrag;           // frag = 128 uint4
  size_t aIdx[KF]; const int8_t* gB[KF]; int8_t* dA[KF]; int8_t* dB[KF];
#pragma unroll
  for (int kc = 0; kc < KF; ++kc) {
    aIdx[kc] = ((size_t)((m0 >> 5) + wave) * Kf + kc) * 128 + lane * 2;
    gB[kc] = Bt + ((size_t)((n0 >> 5) + wave) * Kf + kc) * 1024 + lane * 16;
    dA[kc] = lsA[0] + (kc * 4 + wave) * 1024 + lane * 16;
    dB[kc] = lsB[0] + (kc * 4 + wave) * 1024 + lane * 16;
  }

  const int nsteps = 4096 / (32 * KF);             // 32
  // prologue: stage step 0
#pragma unroll
  for (int kc = 0; kc < KF; ++kc) {
    uint4 a = hA[aIdx[kc]], b = hA[aIdx[kc] + 1];
    uint4 o;
    o.x = q4h(a.x, a.y, s2, m2); o.y = q4h(a.z, a.w, s2, m2);
    o.z = q4h(b.x, b.y, s2, m2); o.w = q4h(b.z, b.w, s2, m2);
    *(uint4*)dA[kc] = o;
    async16(gB[kc], dB[kc]);
  }

  const int mI = (wave & 1) * 2, nI = (wave >> 1) * 2;

  for (int kb = 0; kb < nsteps; ++kb) {
    const int cur = kb & 1;
    const int co = cur * (KF * 4096);
    __syncthreads();
    uint4 pa[KF], pb[KF];
    const bool more = (kb + 1 < nsteps);
    const int po = (cur ^ 1) * (KF * 4096);
    if (more) {
#pragma unroll
      for (int kc = 0; kc < KF; ++kc) {
        const size_t ai = aIdx[kc] + (size_t)(kb + 1) * (KF * 128);
        pa[kc] = hA[ai];
        pb[kc] = hA[ai + 1];
        async16(gB[kc] + (size_t)(kb + 1) * (KF * 1024), dB[kc] + po);
      }
    }
#pragma unroll
    for (int kc = 0; kc < KF; ++kc) {
      v4i af[2], bf[2];
#pragma unroll
      for (int mt = 0; mt < 2; ++mt)
        af[mt] = *(const v4i*)(lsA[0] + co + (kc * 4 + mI + mt) * 1024 + lane * 16);
#pragma unroll
      for (int nt = 0; nt < 2; ++nt)
        bf[nt] = *(const v4i*)(lsB[0] + co + (kc * 4 + nI + nt) * 1024 + lane * 16);
#pragma unroll
      for (int mt = 0; mt < 2; ++mt)
#pragma unroll
        for (int nt = 0; nt < 2; ++nt)
          acc[mt][nt] = __builtin_amdgcn_mfma_i32_32x32x32_i8(af[mt], bf[nt], acc[mt][nt], 0, 0, 0);
    }
    if (more) {
#pragma unroll
      for (int kc = 0; kc < KF; ++kc) {
        uint4 o;
        o.x = q4h(pa[kc].x, pa[kc].y, s2, m2); o.y = q4h(pa[kc].z, pa[kc].w, s2, m2);
        o.z = q4h(pb[kc].x, pb[kc].y, s2, m2); o.w = q4h(pb[kc].z, pb[kc].w, s2, m2);
        *(uint4*)(dA[kc] + po) = o;
      }
    }
  }

  // epilogue: out f32 row-major [8192,1024]
  const int cl = lane & 31;
  const int rbase = 4 * (lane >> 5);
  float bsc[2], bv[2];
#pragma unroll
  for (int nt = 0; nt < 2; ++nt) {
    int col = n0 + wn + nt * 32 + cl;
    bsc[nt] = fmaxf(cmax[col], EPSQ) * (1.0f / 127.0f) * asc;
    bv[nt] = bias[col];
  }
#pragma unroll
  for (int mt = 0; mt < 2; ++mt)
#pragma unroll
    for (int g = 0; g < 4; ++g)
#pragma unroll
      for (int r2 = 0; r2 < 4; ++r2) {
        int row = m0 + wm + mt * 32 + g * 8 + r2 + rbase;
        float* orow = out + (size_t)row * 1024 + n0 + wn + cl;
#pragma unroll
        for (int nt = 0; nt < 2; ++nt)
          orow[nt * 32] = (float)acc[mt][nt][g * 4 + r2] * bsc[nt] + bv[nt];
      }
}

extern "C" void kernel_launch(void* const* d_in, const int* in_sizes, int n_in,
                              void* d_out, int out_size, void* d_ws, size_t ws_size,
                              hipStream_t stream) {
  const float* x  = (const float*)d_in[0];   // [8192,1024]
  const float* mk = (const float*)d_in[1];   // [8192]
  const float* W1 = (const float*)d_in[2];   // [1024,4096]
  const float* b1 = (const float*)d_in[3];   // [4096]
  const float* W2 = (const float*)d_in[4];   // [4096,1024]
  const float* b2 = (const float*)d_in[5];   // [1024]
  float* out = (float*)d_out;                // [8192,1024]

  float* scG   = (float*)d_ws;               // [8]
  float* pmaxX = scG + 8;                    // [1024]
  float* pmaxH = pmaxX + 1024;               // [2048]
  float* pcm1  = pmaxH + 2048;               // [16*4096]
  float* pcm2  = pcm1 + 65536;               // [64*1024]
  float* cm1   = pcm2 + 65536;               // [4096]
  float* cm2   = cm1 + 4096;                 // [1024]
  int8_t* qx  = (int8_t*)(cm2 + 1024);           // 8 MiB  frag order
  int8_t* qw1 = qx  + (size_t)8192 * 1024;       // 4 MiB  frag order [4096 n][1024 k]
  int8_t* qw2 = qw1 + (size_t)4096 * 1024;       // 4 MiB  frag order [1024 n][4096 k]
  unsigned short* h = (unsigned short*)(qw2 + (size_t)1024 * 4096);  // 64 MiB fp16 frag order

  k_stats<<<1152, 256, 0, stream>>>(x, mk, W1, W2, pmaxX, pcm1, pcm2);
  k_quant<<<2560, 256, 0, stream>>>(x, W1, W2, pmaxX, pcm1, pcm2,
                                    qx, qw1, qw2, cm1, cm2, scG);
  gemm1<<<dim3(64, 32), 256, 0, stream>>>(qx, qw1, scG, cm1, b1, mk, h, pmaxH);
  gemm2<<<dim3(64, 8), 256, 0, stream>>>(h, qw2, pmaxH, cm2, b2, out);
}